// Round 1
// baseline (2558.383 us; speedup 1.0000x reference)
//
#include <hip/hip_runtime.h>

typedef unsigned int u32;
typedef unsigned long long u64;
typedef _Float16 f16;
typedef _Float16 f16x8 __attribute__((ext_vector_type(8)));
typedef float f32x4 __attribute__((ext_vector_type(4)));

#define DEV __device__ __forceinline__
#define SCP __HIP_MEMORY_SCOPE_AGENT

// ---------------- workspace layout (bytes), total ~30.8 MB ----------------
constexpr size_t O_XG0   = 0;                               // [512][16][512] f32 : X@Wih0^T + b (permuted cols)
constexpr size_t O_W0HI  = O_XG0  + 512ull*16*512*4;        // [512][128] f16 hi  (Whh0, permuted rows)
constexpr size_t O_W0LO  = O_W0HI + 512ull*128*2;
constexpr size_t O_W1HI  = O_W0LO + 512ull*128*2;           // [512][256] f16 hi  ([Wih1;Whh1] permuted)
constexpr size_t O_W1LO  = O_W1HI + 512ull*256*2;
constexpr size_t O_B1P   = O_W1LO + 512ull*256*2;           // [512] f32 bias1 permuted
constexpr size_t O_MSIG  = O_B1P  + 512*4;                  // [1024][1024] f32 mask*sigmoid(adj_w)
constexpr size_t O_ESC   = O_MSIG + 1024ull*1024*4;         // [16][1024] f32 e_src
constexpr size_t O_EDST  = O_ESC  + 16384*4;                // [16][1024] f32 e_dst
constexpr size_t O_SBUF  = O_EDST + 16384*4;                // [16][1024] f32 s = attn-weighted gf
constexpr size_t O_PREPR = O_SBUF + 16384*4;                // [16][128] f32 price_repr
constexpr size_t O_WFG   = O_PREPR+ 2048*4;                 // [1024][64] f32 folded Wf graph part
constexpr size_t O_H0HI  = O_WFG  + 65536ull*4;             // [513][16][64] u32 (=128 f16) published h0 hi
constexpr size_t O_H0LO  = O_H0HI + 513ull*1024*4;
constexpr size_t O_H1HI  = O_H0LO + 513ull*1024*4;
constexpr size_t O_H1LO  = O_H1HI + 513ull*1024*4;
constexpr size_t O_FLG0  = O_H1LO + 513ull*1024*4;          // [514][32] u32 flags layer0
constexpr size_t O_FLG1  = O_FLG0 + 514ull*32*4;            // [514][32] u32 flags layer1

struct U128 { u64 x, y; };
DEV f16x8 asf16x8(u64 a, u64 b){ U128 t; t.x=a; t.y=b; return __builtin_bit_cast(f16x8, t); }
DEV u32 f16bits(f16 v){ return (u32)__builtin_bit_cast(unsigned short, v); }

DEV float sigm(float x){ x = fminf(fmaxf(x,-30.f),30.f); return __builtin_amdgcn_rcpf(1.f + __expf(-x)); }
DEV float tanh_(float x){ x = fminf(fmaxf(x,-15.f),15.f); float t = __expf(2.f*x); return (t-1.f)*__builtin_amdgcn_rcpf(t+1.f); }

DEV u32 FV(int s){ return 0x5AB00000u + (u32)s; }

// =========================== setup kernel ===========================
__global__ __launch_bounds__(256) void k_setup(
    const float* __restrict__ price, const float* __restrict__ gf,
    const float* __restrict__ amask, const float* __restrict__ Wih0,
    const float* __restrict__ Whh0, const float* __restrict__ bih0, const float* __restrict__ bhh0,
    const float* __restrict__ Wih1, const float* __restrict__ Whh1,
    const float* __restrict__ bih1, const float* __restrict__ bhh1,
    const float* __restrict__ Wg, const float* __restrict__ a_src, const float* __restrict__ a_dst,
    const float* __restrict__ adj_w, const float* __restrict__ Wf,
    char* __restrict__ ws)
{
  const int tid = threadIdx.x;
  const int jb = blockIdx.x;
  __shared__ float P[16][64];
  __shared__ float Wt[64][128];

  if (jb < 2048) {
    // ---- Xg0p GEMM: Xg0p[tt][b][p] = sum_k price[b][tt][k]*Wih0[orow(p)][k] + bih0+bhh0 ----
    const int tt = jb >> 2, p0 = (jb & 3) * 128;
    float* XG = (float*)(ws + O_XG0);
    { int idx = tid*4; int b = idx>>6, k = idx&63;
      f32x4 v = *(const f32x4*)(price + ((size_t)b*512 + tt)*64 + k);
      *(f32x4*)&P[b][k] = v; }
    { int c = tid>>1, kh = (tid&1)*32;
      int p = p0 + c; int row = (p&3)*128 + (p>>2);
      const float* src = Wih0 + row*64 + kh;
      #pragma unroll
      for (int kk=0; kk<32; kk+=4){ f32x4 v = *(const f32x4*)(src+kk);
        Wt[kh+kk+0][c]=v[0]; Wt[kh+kk+1][c]=v[1]; Wt[kh+kk+2][c]=v[2]; Wt[kh+kk+3][c]=v[3]; } }
    __syncthreads();
    { int c = tid & 127, hh2 = tid >> 7;
      int p = p0 + c; int row = (p&3)*128 + (p>>2);
      float bias = bih0[row] + bhh0[row];
      float acc[8];
      #pragma unroll
      for (int r2=0;r2<8;r2++) acc[r2] = bias;
      for (int k=0;k<64;k++){ float w = Wt[k][c];
        #pragma unroll
        for (int r2=0;r2<8;r2++) acc[r2] += w * P[hh2*8+r2][k]; }
      #pragma unroll
      for (int r2=0;r2<8;r2++) XG[((size_t)(tt*16 + hh2*8 + r2))*512 + p0 + c] = acc[r2]; }
  } else if (jb < 3072) {
    // ---- masked_sig = mask * sigmoid(adj_w) ----
    int idx = ((jb-2048)<<10) + tid*4;
    float* MS = (float*)(ws + O_MSIG);
    f32x4 m = *(const f32x4*)(amask+idx); f32x4 a = *(const f32x4*)(adj_w+idx);
    f32x4 o;
    #pragma unroll
    for (int e=0;e<4;e++) o[e] = m[e] * (1.f/(1.f+expf(-a[e])));
    *(f32x4*)(MS+idx) = o;
  } else if (jb < 3136) {
    // ---- Whh0 hi/lo split, permuted rows ----
    unsigned short* HI = (unsigned short*)(ws+O_W0HI);
    unsigned short* LO = (unsigned short*)(ws+O_W0LO);
    int base = ((jb-3072)*256 + tid)*4;
    #pragma unroll
    for (int e=0;e<4;e++){ int idx = base+e; int p = idx>>7, k = idx&127;
      int row = (p&3)*128 + (p>>2);
      float w = Whh0[row*128 + k];
      f16 hi = (f16)w; f16 lo = (f16)((w - (float)hi)*4096.f);
      HI[idx] = (unsigned short)f16bits(hi); LO[idx] = (unsigned short)f16bits(lo); }
  } else if (jb < 3264) {
    // ---- [Wih1 ; Whh1] hi/lo split, permuted rows, K=256 ----
    unsigned short* HI = (unsigned short*)(ws+O_W1HI);
    unsigned short* LO = (unsigned short*)(ws+O_W1LO);
    int base = ((jb-3136)*256 + tid)*4;
    #pragma unroll
    for (int e=0;e<4;e++){ int idx = base+e; int p = idx>>8, k = idx&255;
      int row = (p&3)*128 + (p>>2);
      float w = (k<128) ? Wih1[row*128 + k] : Whh1[row*128 + (k-128)];
      f16 hi = (f16)w; f16 lo = (f16)((w - (float)hi)*4096.f);
      HI[idx] = (unsigned short)f16bits(hi); LO[idx] = (unsigned short)f16bits(lo); }
  } else if (jb < 3265) {
    float* B1 = (float*)(ws+O_B1P);
    for (int p = tid; p < 512; p += 256){ int row = (p&3)*128 + (p>>2); B1[p] = bih1[row]+bhh1[row]; }
  } else if (jb < 3281) {
    // ---- e_src/e_dst scalars (rank-1 collapse) ----
    float cs = 0.f, cd = 0.f;
    for (int g=0; g<64; g++){ cs += Wg[g]*a_src[g]; cd += Wg[g]*a_dst[g]; }
    float* ESC = (float*)(ws+O_ESC); float* EDS = (float*)(ws+O_EDST);
    int base = (jb-3265)*1024 + tid*4;
    f32x4 g4 = *(const f32x4*)(gf+base);
    f32x4 e1, e2;
    #pragma unroll
    for (int e=0;e<4;e++){ e1[e] = g4[e]*cs; e2[e] = g4[e]*cd; }
    *(f32x4*)(ESC+base) = e1; *(f32x4*)(EDS+base) = e2;
  } else if (jb < 3537) {
    // ---- WfG[n][f] = sum_g Wg[g]*Wf[128+64n+g][f] ----
    float* WFG = (float*)(ws+O_WFG);
    int n = (jb-3281)*4 + (tid>>6); int f = tid & 63;
    float acc = 0.f;
    for (int g=0; g<64; g++) acc += Wg[g] * Wf[((size_t)(128 + n*64 + g))*64 + f];
    WFG[n*64 + f] = acc;
  } else {
    // ---- zero h publish slot s=0 ----
    u32* a0 = (u32*)(ws+O_H0HI); u32* a1 = (u32*)(ws+O_H0LO);
    u32* a2 = (u32*)(ws+O_H1HI); u32* a3 = (u32*)(ws+O_H1LO);
    for (int m = tid; m < 1024; m += 256){ a0[m]=0u; a1[m]=0u; a2[m]=0u; a3[m]=0u; }
  }
}

// =========================== LSTM wave ===========================
template<int LAYER>
DEV void lstm_wave(char* __restrict__ ws, int wg, int tid, float* __restrict__ myT)
{
  constexpr int NK = LAYER ? 8 : 4;
  const int lane = tid & 63;
  const int q = lane >> 4, r = lane & 15;
  const int wsub = (tid >> 6) & 1;
  const int T = 2*wg + wsub;          // tile 0..31 of this layer
  const int p0 = T*16;
  const int eb = lane & 15, ejj = lane >> 4;   // epilogue: (batch, h-col-within-tile)

  const float* XG  = (const float*)(ws+O_XG0);
  const u64* W_HI  = (const u64*)(ws + (LAYER? O_W1HI : O_W0HI));
  const u64* W_LO  = (const u64*)(ws + (LAYER? O_W1LO : O_W0LO));
  const u64* H0HI  = (const u64*)(ws+O_H0HI);
  const u64* H0LO  = (const u64*)(ws+O_H0LO);
  const u64* H1HI  = (const u64*)(ws+O_H1HI);
  const u64* H1LO  = (const u64*)(ws+O_H1LO);
  u32* PH_HI = (u32*)(ws + (LAYER? O_H1HI : O_H0HI));
  u32* PH_LO = (u32*)(ws + (LAYER? O_H1LO : O_H0LO));
  u32* FLG0  = (u32*)(ws+O_FLG0);
  u32* FLG1  = (u32*)(ws+O_FLG1);

  // ---- persistent B fragments (weights) in VGPRs ----
  f16x8 Bhi[NK], Blo[NK];
  {
    constexpr int stride64 = LAYER ? 64 : 32;   // u64 per permuted row
    #pragma unroll
    for (int ks=0; ks<NK; ++ks) {
      int o = (p0 + r)*stride64 + ks*8 + q*2;
      Bhi[ks] = asf16x8(W_HI[o], W_HI[o+1]);
      Blo[ks] = asf16x8(W_LO[o], W_LO[o+1]);
    }
  }
  f32x4 bias4 = {0,0,0,0};
  if constexpr (LAYER) bias4 = *(const f32x4*)((const float*)(ws+O_B1P) + p0 + 4*ejj);

  float c = 0.f;
  const int sBeg = LAYER ? 2 : 1, sEnd = LAYER ? 513 : 512;

  for (int s = sBeg; s <= sEnd; ++s) {
    // prefetch input-gate part (layer0) — independent of flags
    f32x4 xg = {0,0,0,0};
    if constexpr (!LAYER) xg = *(const f32x4*)(XG + ((size_t)(s-1)*16 + eb)*512 + p0 + 4*ejj);

    // ---- poll producer flags (per-lane, divergent spin) ----
    {
      const u32* fp = nullptr; u32 tgt = 0;
      if constexpr (!LAYER) {
        if (s>=2 && lane<32) { fp = FLG0 + (s-1)*32 + lane; tgt = FV(s-1); }
      } else {
        if (lane<32)        { fp = FLG0 + (s-1)*32 + lane; tgt = FV(s-1); }
        else if (s>=3)      { fp = FLG1 + (s-2)*32 + (lane-32); tgt = FV(s-2); }
      }
      if (fp) {
        int guard = 1<<24;
        while (__hip_atomic_load(fp, __ATOMIC_RELAXED, SCP) != tgt && --guard) {}
        (void)__hip_atomic_load(fp, __ATOMIC_ACQUIRE, SCP);
      }
    }

    // ---- A fragments: published h (hi/lo f16), device-coherent loads ----
    u64 AH[NK][2], AL[NK][2];
    #pragma unroll
    for (int ks=0; ks<NK; ++ks) {
      const u64 *hA, *lA; int kk, sidx;
      if (LAYER==0 || ks<4) { hA = H0HI; lA = H0LO; kk = ks;   sidx = s-1; }
      else                  { hA = H1HI; lA = H1LO; kk = ks-4; sidx = s-2; }
      int o = sidx*512 + r*32 + kk*8 + q*2;
      AH[ks][0] = __hip_atomic_load(hA+o,   __ATOMIC_RELAXED, SCP);
      AH[ks][1] = __hip_atomic_load(hA+o+1, __ATOMIC_RELAXED, SCP);
      AL[ks][0] = __hip_atomic_load(lA+o,   __ATOMIC_RELAXED, SCP);
      AL[ks][1] = __hip_atomic_load(lA+o+1, __ATOMIC_RELAXED, SCP);
    }

    // ---- split-f16 MFMA: hi*hi + (hi*lo + lo*hi)*2^-12 ----
    f32x4 acch = {0,0,0,0}, accl = {0,0,0,0};
    #pragma unroll
    for (int ks=0; ks<NK; ++ks) {
      f16x8 ah = asf16x8(AH[ks][0], AH[ks][1]);
      f16x8 al = asf16x8(AL[ks][0], AL[ks][1]);
      acch = __builtin_amdgcn_mfma_f32_16x16x32_f16(ah, Bhi[ks], acch, 0,0,0);
      accl = __builtin_amdgcn_mfma_f32_16x16x32_f16(ah, Blo[ks], accl, 0,0,0);
      accl = __builtin_amdgcn_mfma_f32_16x16x32_f16(al, Bhi[ks], accl, 0,0,0);
    }

    // ---- wave-local transpose via LDS: D(row=batch q*4+i, col=r) -> lane(b,jj) ----
    #pragma unroll
    for (int i=0;i<4;i++) myT[(q*4+i)*20 + r] = acch[i] + accl[i]*(1.f/4096.f);
    f32x4 g4 = *(const f32x4*)(myT + eb*20 + 4*ejj);

    float gi = g4[0] + (LAYER ? bias4[0] : xg[0]);
    float gfv= g4[1] + (LAYER ? bias4[1] : xg[1]);
    float gg = g4[2] + (LAYER ? bias4[2] : xg[2]);
    float go = g4[3] + (LAYER ? bias4[3] : xg[3]);
    float I = sigm(gi), Fg = sigm(gfv), G = tanh_(gg), O = sigm(go);
    c = Fg*c + I*G;
    float hv = O * tanh_(c);

    // ---- publish h as packed f16 hi/lo pairs + release flag ----
    const int spub = LAYER ? (s-1) : s;
    f16 hh = (f16)hv;
    f16 hl = (f16)((hv - (float)hh) * 4096.f);
    u32 hhb = f16bits(hh), hlb = f16bits(hl);
    u32 oh = (u32)__shfl_xor((int)hhb, 16, 64);
    u32 ol = (u32)__shfl_xor((int)hlb, 16, 64);
    if ((ejj & 1) == 0) {
      int widx = spub*1024 + eb*64 + 2*T + (ejj>>1);
      __hip_atomic_store(PH_HI+widx, hhb | (oh<<16), __ATOMIC_RELAXED, SCP);
      __hip_atomic_store(PH_LO+widx, hlb | (ol<<16), __ATOMIC_RELAXED, SCP);
    }
    if (LAYER && s==513) ((float*)(ws+O_PREPR))[eb*128 + 4*T + ejj] = hv;
    if (lane == 0) {
      u32* f = (LAYER ? FLG1 : FLG0) + spub*32 + T;
      __hip_atomic_store(f, FV(spub), __ATOMIC_RELEASE, SCP);  // waits own vmem first
    }
  }
}

// =========================== main kernel: LSTM (16 blocks) + attention ===========================
DEV float wredMax(float v){
  #pragma unroll
  for (int o=32;o;o>>=1) v = fmaxf(v, __shfl_xor(v,o,64));
  return v;
}
DEV float wredSum(float v){
  #pragma unroll
  for (int o=32;o;o>>=1) v += __shfl_xor(v,o,64);
  return v;
}

__global__ __launch_bounds__(256) void k_main(const float* __restrict__ gf,
                                              char* __restrict__ ws, float* __restrict__ out)
{
  __shared__ float shT[4][16][20];
  __shared__ float red[4];
  const int tid = threadIdx.x;

  if (blockIdx.x < 16) {
    const int wave = tid >> 6;
    float* myT = &shT[wave][0][0];
    if (tid >> 7) lstm_wave<1>(ws, blockIdx.x, tid, myT);
    else          lstm_wave<0>(ws, blockIdx.x, tid, myT);
    return;
  }

  // ---------------- attention row: softmax + write attn + s accumulation ----------------
  const int row = blockIdx.x - 16;
  const int b = row >> 10, i = row & 1023;
  const float* MSIG = (const float*)(ws+O_MSIG);
  const float* ESC  = (const float*)(ws+O_ESC);
  const float* EDST = (const float*)(ws+O_EDST);
  float* SBUF = (float*)(ws+O_SBUF);

  const float ei = ESC[(b<<10)+i];
  float pv[4];
  float mx = -3.4e38f;
  #pragma unroll
  for (int k2=0;k2<4;k2++){
    int j = tid + (k2<<8);
    float sc = (ei + EDST[(b<<10)+j]) * MSIG[((size_t)i<<10)+j];
    pv[k2] = sc; mx = fmaxf(mx, sc);
  }
  mx = wredMax(mx);
  if ((tid&63)==0) red[tid>>6] = mx;
  __syncthreads();
  mx = fmaxf(fmaxf(red[0],red[1]), fmaxf(red[2],red[3]));
  __syncthreads();

  float sum = 0.f;
  #pragma unroll
  for (int k2=0;k2<4;k2++){ pv[k2] = __expf(pv[k2]-mx); sum += pv[k2]; }
  sum = wredSum(sum);
  if ((tid&63)==0) red[tid>>6] = sum;
  __syncthreads();
  sum = red[0]+red[1]+red[2]+red[3];
  __syncthreads();

  const float rinv = 1.0f / sum;
  float sacc = 0.f;
  const size_t obase = 16 + ((size_t)row << 10);
  #pragma unroll
  for (int k2=0;k2<4;k2++){
    int j = tid + (k2<<8);
    float a = pv[k2]*rinv;
    out[obase + j] = a;
    sacc += a * gf[(b<<10)+j];
  }
  sacc = wredSum(sacc);
  if ((tid&63)==0) red[tid>>6] = sacc;
  __syncthreads();
  if (tid==0) SBUF[row] = red[0]+red[1]+red[2]+red[3];
}

// =========================== final MLP ===========================
__global__ __launch_bounds__(256) void k_mlp(const float* __restrict__ Wf, const float* __restrict__ bf,
  const float* __restrict__ W1, const float* __restrict__ b1,
  const float* __restrict__ W2, const float* __restrict__ b2,
  const char* __restrict__ ws, float* __restrict__ out)
{
  __shared__ float sS[1024];
  __shared__ float sP[128];
  __shared__ float sR[256];
  __shared__ float sF[96];
  const int b = blockIdx.x, tid = threadIdx.x;
  const float* SBUF = (const float*)(ws+O_SBUF);
  const float* PREPR= (const float*)(ws+O_PREPR);
  const float* WFG  = (const float*)(ws+O_WFG);

  { f32x4 v = *(const f32x4*)(SBUF + (b<<10) + tid*4); *(f32x4*)&sS[tid*4] = v; }
  if (tid < 128) sP[tid] = PREPR[b*128 + tid];
  __syncthreads();

  const int f = tid & 63, kq = tid >> 6;
  float acc = 0.f;
  for (int n = kq*256; n < kq*256+256; ++n) acc += sS[n] * WFG[n*64 + f];
  if (kq == 0) {
    for (int k=0;k<128;k++) acc += sP[k] * Wf[k*64 + f];
    acc += bf[f];
  }
  sR[tid] = acc; __syncthreads();
  if (tid < 64) {
    float v = sR[tid] + sR[tid+64] + sR[tid+128] + sR[tid+192];
    sF[tid] = fmaxf(v, 0.f);
  }
  __syncthreads();
  if (tid < 32) {
    float a = 0.f;
    for (int k=0;k<64;k++) a += sF[k] * W1[k*32 + tid];
    sF[64+tid] = fmaxf(a + b1[tid], 0.f);
  }
  __syncthreads();
  if (tid == 0) {
    float a = 0.f;
    for (int k=0;k<32;k++) a += sF[64+k] * W2[k];
    out[b] = a + b2[0];
  }
}

// =========================== launch ===========================
extern "C" void kernel_launch(void* const* d_in, const int* in_sizes, int n_in,
                              void* d_out, int out_size, void* d_ws, size_t ws_size,
                              hipStream_t stream)
{
  const float* price = (const float*)d_in[0];
  const float* gf    = (const float*)d_in[1];
  const float* amask = (const float*)d_in[2];
  const float* Wih0  = (const float*)d_in[3];
  const float* Whh0  = (const float*)d_in[4];
  const float* bih0  = (const float*)d_in[5];
  const float* bhh0  = (const float*)d_in[6];
  const float* Wih1  = (const float*)d_in[7];
  const float* Whh1  = (const float*)d_in[8];
  const float* bih1  = (const float*)d_in[9];
  const float* bhh1  = (const float*)d_in[10];
  const float* Wg    = (const float*)d_in[11];
  const float* asrc  = (const float*)d_in[12];
  const float* adst  = (const float*)d_in[13];
  const float* adjw  = (const float*)d_in[14];
  const float* Wf    = (const float*)d_in[15];
  const float* bf    = (const float*)d_in[16];
  const float* W1    = (const float*)d_in[17];
  const float* b1    = (const float*)d_in[18];
  const float* W2    = (const float*)d_in[19];
  const float* b2    = (const float*)d_in[20];
  char* ws = (char*)d_ws;
  float* out = (float*)d_out;

  k_setup<<<dim3(3538), dim3(256), 0, stream>>>(price, gf, amask, Wih0, Whh0, bih0, bhh0,
                                                Wih1, Whh1, bih1, bhh1, Wg, asrc, adst, adjw, Wf, ws);
  k_main<<<dim3(16 + 16384), dim3(256), 0, stream>>>(gf, ws, out);
  k_mlp<<<dim3(16), dim3(256), 0, stream>>>(Wf, bf, W1, b1, W2, b2, (const char*)ws, out);
}

// Round 2
// 1155.094 us; speedup vs baseline: 2.2149x; 2.2149x over previous
//
#include <hip/hip_runtime.h>

typedef unsigned int u32;
typedef unsigned long long u64;
typedef _Float16 f16;
typedef _Float16 f16x8 __attribute__((ext_vector_type(8)));
typedef float f32x4 __attribute__((ext_vector_type(4)));

#define DEV __device__ __forceinline__
#define SCP __HIP_MEMORY_SCOPE_AGENT

// ---------------- workspace layout (bytes), total ~41.3 MB ----------------
constexpr size_t O_XG0   = 0;                          // [16][512][512] f32 : X@Wih0^T + b0 (permuted cols)
constexpr size_t O_W0HI  = O_XG0   + 16ull*512*512*4;  // [512][128] f16 hi (Whh0 permuted)
constexpr size_t O_W0LO  = O_W0HI  + 512ull*128*2;
constexpr size_t O_WIHHI = O_W0LO  + 512ull*128*2;     // [512][128] f16 hi (Wih1 permuted)
constexpr size_t O_WIHLO = O_WIHHI + 512ull*128*2;
constexpr size_t O_WHHHI = O_WIHLO + 512ull*128*2;     // [512][128] f16 hi (Whh1 permuted)
constexpr size_t O_WHHLO = O_WHHHI + 512ull*128*2;
constexpr size_t O_B1P   = O_WHHLO + 512ull*128*2;     // [512] f32 bias1 permuted
constexpr size_t O_MSIG  = O_B1P   + 512*4;            // [1024][1024] f32 mask*sigmoid(adj_w)
constexpr size_t O_ESC   = O_MSIG  + 1024ull*1024*4;   // [16][1024]
constexpr size_t O_EDST  = O_ESC   + 16384*4;
constexpr size_t O_SBUF  = O_EDST  + 16384*4;          // [16][1024] attn-weighted gf
constexpr size_t O_PREPR = O_SBUF  + 16384*4;          // [16][128] price_repr
constexpr size_t O_WFG   = O_PREPR + 2048*4;           // [1024][64] folded Wf graph part
constexpr size_t O_H0HI  = O_WFG   + 65536ull*4;       // [513][16][64] u32 packed f16 pairs
constexpr size_t O_H0LO  = O_H0HI  + 513ull*16*64*4;
constexpr size_t O_P1    = O_H0LO  + 513ull*16*64*4;   // [513][16][512] f32 Wih1@h0+bias1
constexpr size_t O_FLG0  = O_P1    + 513ull*16*512*4;  // [513][16] u32
constexpr size_t O_FLGP  = O_FLG0  + 513ull*16*4;      // [513] u32

struct U128 { u64 x, y; };
DEV f16x8 asf16x8(u64 a, u64 b){ U128 t; t.x=a; t.y=b; return __builtin_bit_cast(f16x8, t); }
DEV f32x4 asf32x4(u64 a, u64 b){ U128 t; t.x=a; t.y=b; return __builtin_bit_cast(f32x4, t); }
DEV u32 f16bits(f16 v){ return (u32)__builtin_bit_cast(unsigned short, v); }

DEV float sigm(float x){ x = fminf(fmaxf(x,-30.f),30.f); return __builtin_amdgcn_rcpf(1.f + __expf(-x)); }
DEV float tanh_(float x){ x = fminf(fmaxf(x,-15.f),15.f); float t = __expf(2.f*x); return (t-1.f)*__builtin_amdgcn_rcpf(t+1.f); }

DEV u32 FV(int s){ return 0x5AB00000u + (u32)s; }

DEV void spin1(const u32* p, u32 tv){
  int gd = 1<<20;
  while (__hip_atomic_load(p,__ATOMIC_RELAXED,SCP)!=tv && --gd){}
  (void)__hip_atomic_load(p,__ATOMIC_ACQUIRE,SCP);
}

// =========================== setup kernel ===========================
__global__ __launch_bounds__(256) void k_setup(
    const float* __restrict__ price, const float* __restrict__ gf,
    const float* __restrict__ amask, const float* __restrict__ Wih0,
    const float* __restrict__ Whh0, const float* __restrict__ bih0, const float* __restrict__ bhh0,
    const float* __restrict__ Wih1, const float* __restrict__ Whh1,
    const float* __restrict__ bih1, const float* __restrict__ bhh1,
    const float* __restrict__ Wg, const float* __restrict__ a_src, const float* __restrict__ a_dst,
    const float* __restrict__ adj_w, const float* __restrict__ Wf,
    char* __restrict__ ws)
{
  const int tid = threadIdx.x;
  const int jb = blockIdx.x;
  __shared__ float P[16][64];
  __shared__ float Wt[64][128];

  if (jb < 2048) {
    // ---- XG[b][tt][p] = sum_k price[b][tt][k]*Wih0[row(p)][k] + bih0+bhh0 ----
    const int tt = jb >> 2, p0 = (jb & 3) * 128;
    float* XG = (float*)(ws + O_XG0);
    { int idx = tid*4; int b = idx>>6, k = idx&63;
      f32x4 v = *(const f32x4*)(price + ((size_t)b*512 + tt)*64 + k);
      *(f32x4*)&P[b][k] = v; }
    { int c = tid>>1, kh = (tid&1)*32;
      int p = p0 + c; int row = (p&3)*128 + (p>>2);
      const float* src = Wih0 + row*64 + kh;
      #pragma unroll
      for (int kk=0; kk<32; kk+=4){ f32x4 v = *(const f32x4*)(src+kk);
        Wt[kh+kk+0][c]=v[0]; Wt[kh+kk+1][c]=v[1]; Wt[kh+kk+2][c]=v[2]; Wt[kh+kk+3][c]=v[3]; } }
    __syncthreads();
    { int c = tid & 127, hh2 = tid >> 7;
      int p = p0 + c; int row = (p&3)*128 + (p>>2);
      float bias = bih0[row] + bhh0[row];
      float acc[8];
      #pragma unroll
      for (int r2=0;r2<8;r2++) acc[r2] = bias;
      for (int k=0;k<64;k++){ float w = Wt[k][c];
        #pragma unroll
        for (int r2=0;r2<8;r2++) acc[r2] += w * P[hh2*8+r2][k]; }
      #pragma unroll
      for (int r2=0;r2<8;r2++)
        XG[((size_t)(hh2*8+r2)*512 + tt)*512 + p0 + c] = acc[r2]; }
  } else if (jb < 3072) {
    int idx = ((jb-2048)<<10) + tid*4;
    float* MS = (float*)(ws + O_MSIG);
    f32x4 m = *(const f32x4*)(amask+idx); f32x4 a = *(const f32x4*)(adj_w+idx);
    f32x4 o;
    #pragma unroll
    for (int e=0;e<4;e++) o[e] = m[e] * (1.f/(1.f+expf(-a[e])));
    *(f32x4*)(MS+idx) = o;
  } else if (jb < 3136) {
    unsigned short* HI = (unsigned short*)(ws+O_W0HI);
    unsigned short* LO = (unsigned short*)(ws+O_W0LO);
    int base = ((jb-3072)*256 + tid)*4;
    #pragma unroll
    for (int e=0;e<4;e++){ int idx = base+e; int p = idx>>7, k = idx&127;
      int row = (p&3)*128 + (p>>2);
      float w = Whh0[row*128 + k];
      f16 hi = (f16)w; f16 lo = (f16)((w - (float)hi)*4096.f);
      HI[idx] = (unsigned short)f16bits(hi); LO[idx] = (unsigned short)f16bits(lo); }
  } else if (jb < 3200) {
    unsigned short* HI = (unsigned short*)(ws+O_WIHHI);
    unsigned short* LO = (unsigned short*)(ws+O_WIHLO);
    int base = ((jb-3136)*256 + tid)*4;
    #pragma unroll
    for (int e=0;e<4;e++){ int idx = base+e; int p = idx>>7, k = idx&127;
      int row = (p&3)*128 + (p>>2);
      float w = Wih1[row*128 + k];
      f16 hi = (f16)w; f16 lo = (f16)((w - (float)hi)*4096.f);
      HI[idx] = (unsigned short)f16bits(hi); LO[idx] = (unsigned short)f16bits(lo); }
  } else if (jb < 3264) {
    unsigned short* HI = (unsigned short*)(ws+O_WHHHI);
    unsigned short* LO = (unsigned short*)(ws+O_WHHLO);
    int base = ((jb-3200)*256 + tid)*4;
    #pragma unroll
    for (int e=0;e<4;e++){ int idx = base+e; int p = idx>>7, k = idx&127;
      int row = (p&3)*128 + (p>>2);
      float w = Whh1[row*128 + k];
      f16 hi = (f16)w; f16 lo = (f16)((w - (float)hi)*4096.f);
      HI[idx] = (unsigned short)f16bits(hi); LO[idx] = (unsigned short)f16bits(lo); }
  } else if (jb < 3265) {
    float* B1 = (float*)(ws+O_B1P);
    for (int p = tid; p < 512; p += 256){ int row = (p&3)*128 + (p>>2); B1[p] = bih1[row]+bhh1[row]; }
  } else if (jb < 3281) {
    float cs = 0.f, cd = 0.f;
    for (int g=0; g<64; g++){ cs += Wg[g]*a_src[g]; cd += Wg[g]*a_dst[g]; }
    float* ESC = (float*)(ws+O_ESC); float* EDS = (float*)(ws+O_EDST);
    int base = (jb-3265)*1024 + tid*4;
    f32x4 g4 = *(const f32x4*)(gf+base);
    f32x4 e1, e2;
    #pragma unroll
    for (int e=0;e<4;e++){ e1[e] = g4[e]*cs; e2[e] = g4[e]*cd; }
    *(f32x4*)(ESC+base) = e1; *(f32x4*)(EDS+base) = e2;
  } else {
    float* WFG = (float*)(ws+O_WFG);
    int n = (jb-3281)*4 + (tid>>6); int f = tid & 63;
    float acc = 0.f;
    for (int g=0; g<64; g++) acc += Wg[g] * Wf[((size_t)(128 + n*64 + g))*64 + f];
    WFG[n*64 + f] = acc;
  }
}

// =========================== shared-memory block ===========================
struct SM {
  u32 hHI[2][64];     // packed f16 pairs: u32 idx j/2 holds h[j]|h[j+1]<<16
  u32 hLO[2][64];
  float gbuf[8][64];  // per-wave gate staging
  float red[8];       // attention reductions
};

// =========================== per-batch recurrence CU ===========================
// 8 waves; wave w owns p-cols [w*64, w*64+64) as 4 MFMA tiles; M=1 batch (rows replicated).
template<int LAYER>
DEV void rnn_cu(char* __restrict__ ws, int b, int tid, SM* sm)
{
  const int lane = tid & 63, w = tid >> 6;
  const int c = lane & 15, q = lane >> 4;
  const int j = w*16 + c;  // h-col computed in epilogue (replicated over q)

  const u64* WHI = (const u64*)(ws + (LAYER ? O_WHHHI : O_W0HI));
  const u64* WLO = (const u64*)(ws + (LAYER ? O_WHHLO : O_W0LO));
  f16x8 Bhi[4][4], Blo[4][4];
  #pragma unroll
  for (int t=0;t<4;t++)
    #pragma unroll
    for (int ks=0;ks<4;ks++){
      int o = (w*64 + t*16 + c)*32 + ks*8 + q*2;
      Bhi[t][ks] = asf16x8(WHI[o], WHI[o+1]);
      Blo[t][ks] = asf16x8(WLO[o], WLO[o+1]);
    }

  u32* H0HIp = (u32*)(ws+O_H0HI);
  u32* H0LOp = (u32*)(ws+O_H0LO);
  const u64* P1u = (const u64*)(ws+O_P1);
  const u32* FLGPp = (const u32*)(ws+O_FLGP);
  u32* FLG0p = (u32*)(ws+O_FLG0);
  const float* XGb = (const float*)(ws+O_XG0) + (size_t)b*512*512;

  if (q==0 && (c&1)==0){ sm->hHI[0][w*8+(c>>1)] = 0u; sm->hLO[0][w*8+(c>>1)] = 0u; }

  f32x4 xgc = {0,0,0,0}, xgN = {0,0,0,0};
  u64 pc0=0, pc1=0, pn0=0, pn1=0;
  if constexpr (!LAYER) {
    xgc = *(const f32x4*)(XGb + 4*j);
  } else {
    spin1(FLGPp + 1, FV(1));
    size_t o = ((size_t)(1*16 + b)*512 + 4*j) >> 1;
    pc0 = __hip_atomic_load(P1u+o,   __ATOMIC_RELAXED, SCP);
    pc1 = __hip_atomic_load(P1u+o+1, __ATOMIC_RELAXED, SCP);
  }
  u32 huP=0, luP=0;
  float cst = 0.f;
  __syncthreads();
  int cur = 0;

  for (int s=1; s<=512; ++s){
    // ---- deferred global publish of h(s-1) (layer0 only) ----
    if constexpr (!LAYER) {
      if (s>=2 && q==0 && (c&1)==0){
        int o = ((s-1)*16 + b)*64 + w*8 + (c>>1);
        __hip_atomic_store(H0HIp+o, huP, __ATOMIC_RELAXED, SCP);
        __hip_atomic_store(H0LOp+o, luP, __ATOMIC_RELAXED, SCP);
      }
      if (s<512) xgN = *(const f32x4*)(XGb + (size_t)s*512 + 4*j);
    } else {
      if (s<512){
        spin1(FLGPp + (s+1), FV(s+1));  // GEMM runs ahead; usually already set
        size_t o = ((size_t)((s+1)*16 + b)*512 + 4*j) >> 1;
        pn0 = __hip_atomic_load(P1u+o,   __ATOMIC_RELAXED, SCP);
        pn1 = __hip_atomic_load(P1u+o+1, __ATOMIC_RELAXED, SCP);
      }
    }

    // ---- recurrence MFMA from LDS h(s-1), rows replicated ----
    f32x4 acc[4], accl[4];
    #pragma unroll
    for (int t=0;t<4;t++){ acc[t]=f32x4{0,0,0,0}; accl[t]=f32x4{0,0,0,0}; }
    #pragma unroll
    for (int ks=0;ks<4;ks++){
      f16x8 ah  = *(const f16x8*)&sm->hHI[cur][ks*16 + q*4];
      f16x8 al_ = *(const f16x8*)&sm->hLO[cur][ks*16 + q*4];
      #pragma unroll
      for (int t=0;t<4;t++){
        acc[t]  = __builtin_amdgcn_mfma_f32_16x16x32_f16(ah,  Bhi[t][ks], acc[t],  0,0,0);
        accl[t] = __builtin_amdgcn_mfma_f32_16x16x32_f16(ah,  Blo[t][ks], accl[t], 0,0,0);
        accl[t] = __builtin_amdgcn_mfma_f32_16x16x32_f16(al_, Bhi[t][ks], accl[t], 0,0,0);
      }
    }

    // ---- wave-local gate staging (rows identical -> reg 0) ----
    if (q==0){
      #pragma unroll
      for (int t=0;t<4;t++) sm->gbuf[w][t*16+c] = acc[t][0] + accl[t][0]*(1.f/4096.f);
    }
    f32x4 g4 = *(const f32x4*)&sm->gbuf[w][4*c];   // same-wave ds dep, lgkm-ordered
    f32x4 add = LAYER ? asf32x4(pc0,pc1) : xgc;
    float I = sigm(g4[0]+add[0]);
    float F = sigm(g4[1]+add[1]);
    float G = tanh_(g4[2]+add[2]);
    float O = sigm(g4[3]+add[3]);
    cst = F*cst + I*G;
    float hv = O * tanh_(cst);

    // ---- pack h(s) and write to LDS (next buffer) ----
    f16 hh = (f16)hv; f16 hl = (f16)((hv - (float)hh)*4096.f);
    u32 hb = f16bits(hh), lb = f16bits(hl);
    u32 oh = (u32)__shfl_xor((int)hb, 1, 64);
    u32 ol = (u32)__shfl_xor((int)lb, 1, 64);
    u32 hu = hb | (oh<<16), lu = lb | (ol<<16);
    int nxt = cur^1;
    if (q==0 && (c&1)==0){ sm->hHI[nxt][w*8+(c>>1)] = hu; sm->hLO[nxt][w*8+(c>>1)] = lu; }
    if constexpr (LAYER){ if (s==512 && q==0) ((float*)(ws+O_PREPR))[b*128 + j] = hv; }

    if constexpr (!LAYER){ asm volatile("s_waitcnt vmcnt(0)" ::: "memory"); }
    __syncthreads();   // drains each wave's vmem (incl. h(s-1) stores) before barrier
    if constexpr (!LAYER){
      if (s>=2 && tid==0)
        __hip_atomic_store(FLG0p + (s-1)*16 + b, FV(s-1), __ATOMIC_RELAXED, SCP);
    }
    huP=hu; luP=lu; cur = nxt; xgc = xgN; pc0=pn0; pc1=pn1;
  }

  if constexpr (!LAYER){
    if (q==0 && (c&1)==0){
      int o = (512*16 + b)*64 + w*8 + (c>>1);
      __hip_atomic_store(H0HIp+o, huP, __ATOMIC_RELAXED, SCP);
      __hip_atomic_store(H0LOp+o, luP, __ATOMIC_RELAXED, SCP);
    }
    asm volatile("s_waitcnt vmcnt(0)" ::: "memory");
    __syncthreads();
    if (tid==0) __hip_atomic_store(FLG0p + 512*16 + b, FV(512), __ATOMIC_RELAXED, SCP);
  }
}

// =========================== GEMM CU: P1(s) = Wih1 @ h0(s) + bias1, all 16 batches ===========================
DEV void gemm_cu(char* __restrict__ ws, int g, int tid)
{
  const int lane = tid & 63, w = tid >> 6;
  const int c = lane & 15, q = lane >> 4;

  const u64* WHI = (const u64*)(ws+O_WIHHI);
  const u64* WLO = (const u64*)(ws+O_WIHLO);
  f16x8 Bhi[4][4], Blo[4][4];
  #pragma unroll
  for (int t=0;t<4;t++)
    #pragma unroll
    for (int ks=0;ks<4;ks++){
      int o = (w*64 + t*16 + c)*32 + ks*8 + q*2;
      Bhi[t][ks] = asf16x8(WHI[o], WHI[o+1]);
      Blo[t][ks] = asf16x8(WLO[o], WLO[o+1]);
    }
  float bias_t[4];
  #pragma unroll
  for (int t=0;t<4;t++) bias_t[t] = ((const float*)(ws+O_B1P))[w*64 + t*16 + c];

  const u64* H0HIu = (const u64*)(ws+O_H0HI);
  const u64* H0LOu = (const u64*)(ws+O_H0LO);
  const u32* FLG0p = (const u32*)(ws+O_FLG0);
  u32* FLGPp = (u32*)(ws+O_FLGP);
  float* P1f = (float*)(ws+O_P1);

  for (int s = 1+g; s <= 512; s += 3){
    // wait for all 16 batch producers
    { const u32* fp = FLG0p + s*16 + c; int gd = 1<<20; u32 tv = FV(s);
      for(;;){ bool ok = (lane>=16) || (__hip_atomic_load(fp,__ATOMIC_RELAXED,SCP)==tv);
               if (__all(ok) || !--gd) break; }
      (void)__hip_atomic_load(fp, __ATOMIC_ACQUIRE, SCP); }

    u64 AH[4][2], AL[4][2];
    #pragma unroll
    for (int ks=0;ks<4;ks++){
      size_t o = ((size_t)(s*16 + c))*32 + ks*8 + q*2;   // A row = batch = lane&15
      AH[ks][0]=__hip_atomic_load(H0HIu+o,  __ATOMIC_RELAXED,SCP);
      AH[ks][1]=__hip_atomic_load(H0HIu+o+1,__ATOMIC_RELAXED,SCP);
      AL[ks][0]=__hip_atomic_load(H0LOu+o,  __ATOMIC_RELAXED,SCP);
      AL[ks][1]=__hip_atomic_load(H0LOu+o+1,__ATOMIC_RELAXED,SCP);
    }
    f32x4 acc[4], accl[4];
    #pragma unroll
    for (int t=0;t<4;t++){ acc[t]=f32x4{0,0,0,0}; accl[t]=f32x4{0,0,0,0}; }
    #pragma unroll
    for (int ks=0;ks<4;ks++){
      f16x8 ah  = asf16x8(AH[ks][0], AH[ks][1]);
      f16x8 al_ = asf16x8(AL[ks][0], AL[ks][1]);
      #pragma unroll
      for (int t=0;t<4;t++){
        acc[t]  = __builtin_amdgcn_mfma_f32_16x16x32_f16(ah,  Bhi[t][ks], acc[t],  0,0,0);
        accl[t] = __builtin_amdgcn_mfma_f32_16x16x32_f16(ah,  Blo[t][ks], accl[t], 0,0,0);
        accl[t] = __builtin_amdgcn_mfma_f32_16x16x32_f16(al_, Bhi[t][ks], accl[t], 0,0,0);
      }
    }
    #pragma unroll
    for (int t=0;t<4;t++){
      #pragma unroll
      for (int i=0;i<4;i++){
        float v = acc[t][i] + accl[t][i]*(1.f/4096.f) + bias_t[t];
        __hip_atomic_store(P1f + ((size_t)(s*16 + q*4 + i))*512 + w*64 + t*16 + c,
                           v, __ATOMIC_RELAXED, SCP);
      }
    }
    asm volatile("s_waitcnt vmcnt(0)" ::: "memory");
    __syncthreads();
    if (tid==0) __hip_atomic_store(FLGPp + s, FV(s), __ATOMIC_RELAXED, SCP);
  }
}

// =========================== main kernel ===========================
DEV float wredMax(float v){
  #pragma unroll
  for (int o=32;o;o>>=1) v = fmaxf(v, __shfl_xor(v,o,64));
  return v;
}
DEV float wredSum(float v){
  #pragma unroll
  for (int o=32;o;o>>=1) v += __shfl_xor(v,o,64);
  return v;
}

__global__ __launch_bounds__(512,2) void k_main(const float* __restrict__ gf,
                                               char* __restrict__ ws, float* __restrict__ out)
{
  __shared__ SM sm;
  const int tid = threadIdx.x;
  const int bid = blockIdx.x;

  if (bid < 16) { rnn_cu<0>(ws, bid, tid, &sm); return; }
  if (bid < 32) { rnn_cu<1>(ws, bid-16, tid, &sm); return; }
  if (bid < 35) { gemm_cu(ws, bid-32, tid); return; }

  // ---------------- attention row: softmax + write attn + s accumulation ----------------
  const int row = bid - 35;
  const int b = row >> 10, i = row & 1023;
  const int w = tid >> 6;
  const float* MSIG = (const float*)(ws+O_MSIG);
  const float* ESC  = (const float*)(ws+O_ESC);
  const float* EDST = (const float*)(ws+O_EDST);
  float* SBUF = (float*)(ws+O_SBUF);

  const float ei = ESC[(b<<10)+i];
  float pv[2];
  float mx = -3.4e38f;
  #pragma unroll
  for (int k2=0;k2<2;k2++){
    int jj = tid + (k2<<9);
    float sc = (ei + EDST[(b<<10)+jj]) * MSIG[((size_t)i<<10)+jj];
    pv[k2] = sc; mx = fmaxf(mx, sc);
  }
  mx = wredMax(mx);
  if ((tid&63)==0) sm.red[w] = mx;
  __syncthreads();
  mx = fmaxf(fmaxf(fmaxf(sm.red[0],sm.red[1]),fmaxf(sm.red[2],sm.red[3])),
             fmaxf(fmaxf(sm.red[4],sm.red[5]),fmaxf(sm.red[6],sm.red[7])));
  __syncthreads();

  float sum = 0.f;
  #pragma unroll
  for (int k2=0;k2<2;k2++){ pv[k2] = __expf(pv[k2]-mx); sum += pv[k2]; }
  sum = wredSum(sum);
  if ((tid&63)==0) sm.red[w] = sum;
  __syncthreads();
  sum = sm.red[0]+sm.red[1]+sm.red[2]+sm.red[3]+sm.red[4]+sm.red[5]+sm.red[6]+sm.red[7];
  __syncthreads();

  const float rinv = 1.0f / sum;
  float sacc = 0.f;
  const size_t obase = 16 + ((size_t)row << 10);
  #pragma unroll
  for (int k2=0;k2<2;k2++){
    int jj = tid + (k2<<9);
    float a = pv[k2]*rinv;
    out[obase + jj] = a;
    sacc += a * gf[(b<<10)+jj];
  }
  sacc = wredSum(sacc);
  if ((tid&63)==0) sm.red[w] = sacc;
  __syncthreads();
  if (tid==0) SBUF[row] = sm.red[0]+sm.red[1]+sm.red[2]+sm.red[3]
                        + sm.red[4]+sm.red[5]+sm.red[6]+sm.red[7];
}

// =========================== final MLP ===========================
__global__ __launch_bounds__(256) void k_mlp(const float* __restrict__ Wf, const float* __restrict__ bf,
  const float* __restrict__ W1, const float* __restrict__ b1,
  const float* __restrict__ W2, const float* __restrict__ b2,
  const char* __restrict__ ws, float* __restrict__ out)
{
  __shared__ float sS[1024];
  __shared__ float sP[128];
  __shared__ float sR[256];
  __shared__ float sF[96];
  const int b = blockIdx.x, tid = threadIdx.x;
  const float* SBUF = (const float*)(ws+O_SBUF);
  const float* PREPR= (const float*)(ws+O_PREPR);
  const float* WFG  = (const float*)(ws+O_WFG);

  { f32x4 v = *(const f32x4*)(SBUF + (b<<10) + tid*4); *(f32x4*)&sS[tid*4] = v; }
  if (tid < 128) sP[tid] = PREPR[b*128 + tid];
  __syncthreads();

  const int f = tid & 63, kq = tid >> 6;
  float acc = 0.f;
  for (int n = kq*256; n < kq*256+256; ++n) acc += sS[n] * WFG[n*64 + f];
  if (kq == 0) {
    for (int k=0;k<128;k++) acc += sP[k] * Wf[k*64 + f];
    acc += bf[f];
  }
  sR[tid] = acc; __syncthreads();
  if (tid < 64) {
    float v = sR[tid] + sR[tid+64] + sR[tid+128] + sR[tid+192];
    sF[tid] = fmaxf(v, 0.f);
  }
  __syncthreads();
  if (tid < 32) {
    float a = 0.f;
    for (int k=0;k<64;k++) a += sF[k] * W1[k*32 + tid];
    sF[64+tid] = fmaxf(a + b1[tid], 0.f);
  }
  __syncthreads();
  if (tid == 0) {
    float a = 0.f;
    for (int k=0;k<32;k++) a += sF[64+k] * W2[k];
    out[b] = a + b2[0];
  }
}

// =========================== launch ===========================
extern "C" void kernel_launch(void* const* d_in, const int* in_sizes, int n_in,
                              void* d_out, int out_size, void* d_ws, size_t ws_size,
                              hipStream_t stream)
{
  const float* price = (const float*)d_in[0];
  const float* gf    = (const float*)d_in[1];
  const float* amask = (const float*)d_in[2];
  const float* Wih0  = (const float*)d_in[3];
  const float* Whh0  = (const float*)d_in[4];
  const float* bih0  = (const float*)d_in[5];
  const float* bhh0  = (const float*)d_in[6];
  const float* Wih1  = (const float*)d_in[7];
  const float* Whh1  = (const float*)d_in[8];
  const float* bih1  = (const float*)d_in[9];
  const float* bhh1  = (const float*)d_in[10];
  const float* Wg    = (const float*)d_in[11];
  const float* asrc  = (const float*)d_in[12];
  const float* adst  = (const float*)d_in[13];
  const float* adjw  = (const float*)d_in[14];
  const float* Wf    = (const float*)d_in[15];
  const float* bf    = (const float*)d_in[16];
  const float* W1    = (const float*)d_in[17];
  const float* b1    = (const float*)d_in[18];
  const float* W2    = (const float*)d_in[19];
  const float* b2    = (const float*)d_in[20];
  char* ws = (char*)d_ws;
  float* out = (float*)d_out;

  k_setup<<<dim3(3537), dim3(256), 0, stream>>>(price, gf, amask, Wih0, Whh0, bih0, bhh0,
                                                Wih1, Whh1, bih1, bhh1, Wg, asrc, adst, adjw, Wf, ws);
  k_main<<<dim3(35 + 16384), dim3(512), 0, stream>>>(gf, ws, out);
  k_mlp<<<dim3(16), dim3(256), 0, stream>>>(Wf, bf, W1, b1, W2, b2, (const char*)ws, out);
}